// Round 20
// baseline (61.113 us; speedup 1.0000x reference)
//
#include <hip/hip_runtime.h>
#include <math.h>
#include <stdint.h>

#define NP 288               // 274 padded to 18*16
#define OUT_H (2*512*64)

typedef _Float16 f16;
typedef __attribute__((ext_vector_type(2))) _Float16 f16x2;
typedef __attribute__((ext_vector_type(4))) _Float16 f16x4;
typedef __attribute__((ext_vector_type(8))) _Float16 f16x8;
typedef __attribute__((ext_vector_type(4))) float f32x4;

static __device__ __forceinline__ f16x2 pkrtz(float a, float b) {
    return __builtin_bit_cast(f16x2, __builtin_amdgcn_cvt_pkrtz(a, b));
}

#if defined(__has_builtin)
#if __has_builtin(__builtin_amdgcn_mfma_f32_16x16x16f16)
#define HAVE_MFMA16 1
#endif
#endif

static __device__ __forceinline__ f32x4 mfma16(f16x4 a, f16x4 b, f32x4 c) {
#ifdef HAVE_MFMA16
    return __builtin_amdgcn_mfma_f32_16x16x16f16(a, b, c, 0, 0, 0);
#else
    f32x4 d;
    asm volatile("v_mfma_f32_16x16x16_f16 %0, %1, %2, %3\n\ts_nop 7\n\ts_nop 7"
                 : "=v"(d) : "v"(a), "v"(b), "v"(c));
    return d;
#endif
}

// relu + pack f32x4 -> f16x4 (pkrtz monotone & exact at 0 -> pack-then-max ok)
static __device__ __forceinline__ f16x4 relupack(f32x4 h) {
    f16x2 lo = pkrtz(h[0], h[1]);
    f16x2 hi = pkrtz(h[2], h[3]);
    const f16x2 z = {(_Float16)0, (_Float16)0};
    lo = __builtin_elementwise_max(lo, z);
    hi = __builtin_elementwise_max(hi, z);
    return __builtin_shufflevector(lo, hi, 0, 1, 2, 3);
}

// ---------------------------------------------------------------------------
// Kernel A: precompute (identical to round 18)
//   Q1[n][288] f16  = b1e + feats[n] @ w1e[0:64]   (i-side, includes bias)
//   P2F f32 [b][32jt][18S][64lane]x4 = C-fragment-ordered j-side projection
//   W2F[18][64]x4 f16 = per-lane B2 fragments
//   W1CB[4][16][32] f16 = w1c^T blocks (coor-MLP A-frag source)
//   A1B[18][64]x4 f16 = i-independent A1 frags (Wd rows; Q1 slot zeroed)
// ---------------------------------------------------------------------------
__global__ __launch_bounds__(256) void egnn_pre(
    const float* __restrict__ feats, const float* __restrict__ w1e,
    const float* __restrict__ b1e,   const float* __restrict__ w2e,
    const float* __restrict__ w1c,
    f16* __restrict__ Q1, float* __restrict__ P2F,
    f16* __restrict__ W2F, f16* __restrict__ W1CB, f16* __restrict__ A1B)
{
    int id = blockIdx.x * 256 + threadIdx.x;
    const int NN = 1024 * NP;
    if (id < 2 * NN) {
        int hf = id / NN, r = id % NN;
        int n = r / NP, e = r % NP;
        float a = 0.f;
        if (e < 274) {
            a = hf ? 0.f : b1e[e];
            const float* fp = feats + n * 64;
            const float* wp = w1e + hf * 64 * 274 + e;
            #pragma unroll 8
            for (int d2 = 0; d2 < 64; ++d2) a += fp[d2] * wp[d2 * 274];
        }
        if (hf) {
            int b = n >> 9, j = n & 511;
            int jt = j >> 4, cl = j & 15;
            int S = e >> 4, gg = (e >> 2) & 3, jj = e & 3;
            P2F[(((b * 32 + jt) * 18 + S) * 64 + (cl + 16 * gg)) * 4 + jj] = a;
        } else {
            Q1[n * NP + e] = (f16)a;
        }
    } else {
        int x = id - 2 * NN;
        if (x < 1152) {
            // W2F
            int S = x >> 6, l = x & 63, cc = l & 15, gg = l >> 4;
            f16x4 v = {0, 0, 0, 0};
            #pragma unroll
            for (int jj = 0; jj < 4; ++jj) {
                int e = S * 16 + gg * 4 + jj;
                v[jj] = (f16)(e < 274 ? w2e[e * 16 + cc] : 0.f);
            }
            *(f16x4*)(W2F + x * 4) = v;
        } else if (x < 1152 + 2048) {
            int y = x - 1152;
            int T = y >> 9, rem = y & 511, c2 = rem >> 5, k = rem & 31;
            W1CB[y] = (f16)(k < 16 ? w1c[k * 64 + T * 16 + c2] : 0.f);
        } else if (x < 1152 + 2048 + 1152) {
            // A1B (i-independent part of A1 frags)
            int y = x - 1152 - 2048;
            int S = y >> 6, l = y & 63, cc = l & 15, gg = l >> 4;
            int e = S * 16 + cc;
            f16x4 v = {0, 0, 0, 0};
            if (e < 274) {
                if (gg == 0) {
                    v[0] = (f16)w1e[128 * 274 + e]; v[1] = (f16)w1e[129 * 274 + e];
                    v[2] = (f16)w1e[130 * 274 + e]; v[3] = (f16)w1e[131 * 274 + e];
                } else if (gg == 1) {
                    v[0] = (f16)w1e[132 * 274 + e]; v[1] = (f16)w1e[133 * 274 + e];
                    v[2] = (f16)w1e[134 * 274 + e]; v[3] = (f16)w1e[135 * 274 + e];
                } else if (gg == 2) {
                    v[0] = (f16)w1e[136 * 274 + e]; // v[1] = Q1 slot, inserted per block
                }
            }
            *(f16x4*)(A1B + y * 4) = v;
        }
    }
}

// ---------------------------------------------------------------------------
// Kernel B: one block per (b,i) — 1024 blocks, 4 waves x 128 j each.
// Phase 1: 4-unit ILP per S-step (4 independent h-chains + 4 acc-chains
//   interleave -> hazard latency between MFMA<->VALU amortized 4x), 1-gen
//   named-register f32-frag prefetch (no ring indexing -> no scratch).
// Phase 2: coor MLP via MFMA, reductions, node MLP.
// ---------------------------------------------------------------------------
__global__ __launch_bounds__(256) void egnn_edge(
    const float* __restrict__ feats, const float* __restrict__ coors,
    const float* __restrict__ b2e,   const float* __restrict__ b1c,
    const float* __restrict__ w2c,   const float* __restrict__ b2cv,
    const float* __restrict__ w1h,   const float* __restrict__ b1h,
    const float* __restrict__ w2h,   const float* __restrict__ b2h,
    const f16* __restrict__ Q1,  const float* __restrict__ P2F,
    const f16* __restrict__ W2F, const f16* __restrict__ W1CB,
    const f16* __restrict__ A1B, float* __restrict__ out)
{
    __shared__ f16x4 sA1f[1152];        // 9216 B
    __shared__ f16x4 sB2f[1152];        // 9216 B
    __shared__ __align__(16) f16 sM[512 * 16];   // 16384 B
    __shared__ float sHid[128];
    __shared__ float sRedM[4][16];
    __shared__ float sRedC[4][3];
    __shared__ float sFin[16];

    const int bi = blockIdx.x, bb = bi >> 9;
    const int t = threadIdx.x;
    const int lane = t & 63, wv = t >> 6;
    const int c = lane & 15, g = lane >> 4;

    // ---- block init: coalesced copies + per-i Q1 insert (looped: 288>256) --
    {
        const uint2* srcA = (const uint2*)A1B;
        const uint2* srcB = (const uint2*)W2F;
        uint2* dstA = (uint2*)sA1f;
        uint2* dstB = (uint2*)sB2f;
        for (int x = t; x < 1152; x += 256) { dstA[x] = srcA[x]; dstB[x] = srcB[x]; }
    }
    __syncthreads();
    {
        const f16* Q1r = Q1 + bi * NP;
        for (int x = t; x < 288; x += 256) {
            int S = x >> 4, cc = x & 15;
            sA1f[S * 64 + 32 + cc][1] = Q1r[S * 16 + cc];
        }
    }
    const float b2e_c = b2e[c];
    const float cix = coors[bi * 3 + 0];
    const float ciy = coors[bi * 3 + 1];
    const float ciz = coors[bi * 3 + 2];
    __syncthreads();

    const float* P2Fb = P2F + (bb << 5) * 18 * 256;   // [32jt][18S][256] f32

    // ========== Phase 1: edge MLP, 4-unit ILP + 1-gen named prefetch ========
    #pragma unroll 1
    for (int G = 0; G < 2; ++G) {
        const int jbase = wv * 128 + G * 64;
        f16x4 b1u[4];
        const float* cpp[4];
        #pragma unroll
        for (int u = 0; u < 4; ++u) {
            const int jt = (jbase >> 4) + u;
            const int j = jbase + u * 16 + c;
            const int jg = (bb << 9) + j;
            float rx = cix - coors[jg * 3 + 0];
            float ry = ciy - coors[jg * 3 + 1];
            float rz = ciz - coors[jg * 3 + 2];
            float sq = rx * rx + ry * ry + rz * rz;
            float d = sq > 0.f ? sqrtf(sq) : 0.f;
            // enc via 1 sincos + double-angle ladder (d/8 -> d/4 -> d/2 -> d)
            float s8, c8v;
            __sincosf(d * 0.125f, &s8, &c8v);
            float s4 = 2.f * s8 * c8v, c4v = 1.f - 2.f * s8 * s8;
            float s2 = 2.f * s4 * c4v, c2v = 1.f - 2.f * s4 * s4;
            float s1 = 2.f * s2 * c2v, c1v = 1.f - 2.f * s2 * s2;
            f16x2 p01 = pkrtz(s1, s2);     // sin(d), sin(d/2)
            f16x2 p23 = pkrtz(s4, s8);     // sin(d/4), sin(d/8)
            f16x2 p45 = pkrtz(c1v, c2v);   // cos(d), cos(d/2)
            f16x2 p67 = pkrtz(c4v, c8v);   // cos(d/4), cos(d/8)
            f16x2 pd1 = pkrtz(d, 1.0f);
            f16x2 zz = {(_Float16)0, (_Float16)0};
            f16x2 lo = (g == 0) ? p01 : (g == 1) ? p45 : (g == 2) ? pd1 : zz;
            f16x2 hi = (g == 0) ? p23 : (g == 1) ? p67 : zz;
            b1u[u] = __builtin_shufflevector(lo, hi, 0, 1, 2, 3);
            cpp[u] = P2Fb + jt * 18 * 256 + lane * 4;
        }

        f32x4 acc0 = {0,0,0,0}, acc1 = {0,0,0,0};
        f32x4 acc2 = {0,0,0,0}, acc3 = {0,0,0,0};
        // prologue: S=0 frags, all 4 units (named regs)
        f32x4 cA = *(const f32x4*)(cpp[0]);
        f32x4 cB = *(const f32x4*)(cpp[1]);
        f32x4 cC = *(const f32x4*)(cpp[2]);
        f32x4 cD = *(const f32x4*)(cpp[3]);

        #pragma unroll 2
        for (int S = 0; S < 18; ++S) {
            f32x4 nA = cA, nB = cB, nC = cC, nD = cD;
            if (S < 17) {
                nA = *(const f32x4*)(cpp[0] + (S + 1) * 256);
                nB = *(const f32x4*)(cpp[1] + (S + 1) * 256);
                nC = *(const f32x4*)(cpp[2] + (S + 1) * 256);
                nD = *(const f32x4*)(cpp[3] + (S + 1) * 256);
            }
            f16x4 a1 = sA1f[S * 64 + lane];
            f16x4 b2 = sB2f[S * 64 + lane];
            f32x4 h0 = mfma16(a1, b1u[0], cA);
            f32x4 h1 = mfma16(a1, b1u[1], cB);
            f32x4 h2 = mfma16(a1, b1u[2], cC);
            f32x4 h3 = mfma16(a1, b1u[3], cD);
            acc0 = mfma16(relupack(h0), b2, acc0);
            acc1 = mfma16(relupack(h1), b2, acc1);
            acc2 = mfma16(relupack(h2), b2, acc2);
            acc3 = mfma16(relupack(h3), b2, acc3);
            cA = nA; cB = nB; cC = nC; cD = nD;
        }

        #pragma unroll
        for (int u = 0; u < 4; ++u) {
            const int jr = jbase + u * 16 + g * 4;
            const f32x4 accu = (u == 0) ? acc0 : (u == 1) ? acc1
                              : (u == 2) ? acc2 : acc3;
            #pragma unroll
            for (int r = 0; r < 4; ++r)
                sM[(jr + r) * 16 + c] = (f16)(accu[r] + b2e_c);
        }
    }
    __syncthreads();

    // ================= Phase 2: coor MLP via MFMA =================
    f16x8 aW[4];
    f32x4 b1cL[4], w2cL[4];
    #pragma unroll
    for (int T = 0; T < 4; ++T) {
        aW[T] = *(const f16x8*)(W1CB + (T * 16 + c) * 32 + g * 8);
        b1cL[T] = *(const f32x4*)(b1c + T * 16 + g * 4);
        w2cL[T] = *(const f32x4*)(w2c + T * 16 + g * 4);
    }
    const float b2c0 = b2cv[0];

    float cax = 0.f, cay = 0.f, caz = 0.f;
    float macc8[8] = {0.f,0.f,0.f,0.f,0.f,0.f,0.f,0.f};

    #pragma unroll 1
    for (int jt = 0; jt < 8; ++jt) {
        const int jrow = wv * 128 + jt * 16;
        f16x8 bm = {0,0,0,0,0,0,0,0};
        if (g < 2) {
            bm = *(const f16x8*)(sM + (jrow + c) * 16 + g * 8);
            #pragma unroll
            for (int p = 0; p < 8; ++p) macc8[p] += (float)bm[p];
        }
        f32x4 zc = {0,0,0,0};
        float cwp = 0.f;
        #pragma unroll
        for (int T = 0; T < 4; ++T) {
            f32x4 hd = __builtin_amdgcn_mfma_f32_16x16x32_f16(aW[T], bm, zc, 0, 0, 0);
            #pragma unroll
            for (int r = 0; r < 4; ++r)
                cwp += fmaxf(hd[r] + b1cL[T][r], 0.f) * w2cL[T][r];
        }
        cwp += __shfl_xor(cwp, 16);
        cwp += __shfl_xor(cwp, 32);
        float cw = cwp + b2c0;

        int jg = (bb << 9) + jrow + c;
        float rx = cix - coors[jg * 3 + 0];
        float ry = ciy - coors[jg * 3 + 1];
        float rz = ciz - coors[jg * 3 + 2];
        cax += cw * rx; cay += cw * ry; caz += cw * rz;
    }

    // m_i: reduce macc8 over the 16 c-lanes (butterfly)
    #pragma unroll
    for (int msk = 1; msk <= 8; msk <<= 1)
        #pragma unroll
        for (int p = 0; p < 8; ++p) macc8[p] += __shfl_xor(macc8[p], msk);
    if (c == 0 && g < 2) {
        #pragma unroll
        for (int p = 0; p < 8; ++p) sRedM[wv][g * 8 + p] = macc8[p];
    }
    // coors: full-wave reduce (each edge counted 4x -> scale 0.25 at the end)
    #pragma unroll
    for (int msk = 1; msk <= 32; msk <<= 1) {
        cax += __shfl_xor(cax, msk);
        cay += __shfl_xor(cay, msk);
        caz += __shfl_xor(caz, msk);
    }
    if (lane == 0) { sRedC[wv][0] = cax; sRedC[wv][1] = cay; sRedC[wv][2] = caz; }
    __syncthreads();

    if (t < 16) sFin[t] = sRedM[0][t] + sRedM[1][t] + sRedM[2][t] + sRedM[3][t];
    if (t >= 32 && t < 35) {
        int k = t - 32;
        out[OUT_H + bi * 3 + k] =
            (sRedC[0][k] + sRedC[1][k] + sRedC[2][k] + sRedC[3][k]) * 0.25f;
    }
    __syncthreads();

    // ================= node MLP =================
    if (t < 128) {
        float a = b1h[t];
        const float* fp = feats + bi * 64;
        #pragma unroll 8
        for (int k = 0; k < 64; ++k) a += fp[k] * w1h[k * 128 + t];
        #pragma unroll
        for (int k = 0; k < 16; ++k) a += sFin[k] * w1h[(64 + k) * 128 + t];
        sHid[t] = fmaxf(a, 0.f);
    }
    __syncthreads();
    if (t < 64) {
        float a = b2h[t];
        #pragma unroll 8
        for (int k = 0; k < 128; ++k) a += sHid[k] * w2h[k * 64 + t];
        out[bi * 64 + t] = a;
    }
}

extern "C" void kernel_launch(void* const* d_in, const int* in_sizes, int n_in,
                              void* d_out, int out_size, void* d_ws, size_t ws_size,
                              hipStream_t stream)
{
    const float* feats = (const float*)d_in[0];
    const float* coors = (const float*)d_in[1];
    const float* w1e   = (const float*)d_in[2];
    const float* b1e   = (const float*)d_in[3];
    const float* w2e   = (const float*)d_in[4];
    const float* b2e   = (const float*)d_in[5];
    const float* w1c   = (const float*)d_in[6];
    const float* b1c   = (const float*)d_in[7];
    const float* w2c   = (const float*)d_in[8];
    const float* b2c   = (const float*)d_in[9];
    const float* w1h   = (const float*)d_in[10];
    const float* b1h   = (const float*)d_in[11];
    const float* w2h   = (const float*)d_in[12];
    const float* b2h   = (const float*)d_in[13];
    float* out = (float*)d_out;

    char* ws = (char*)d_ws;
    f16*   Q1    = (f16*)ws;                        // 589824 B
    float* P2F   = (float*)(ws + 589824);           // 1179648 B (frag order, f32)
    f16*   W2F   = (f16*)(ws + 1769472);            // 9216 B
    f16*   W1CB  = (f16*)(ws + 1778688);            // 4096 B
    f16*   A1B   = (f16*)(ws + 1782784);            // 9216 B

    egnn_pre<<<2321, 256, 0, stream>>>(feats, w1e, b1e, w2e, w1c,
                                       Q1, P2F, W2F, W1CB, A1B);
    egnn_edge<<<1024, 256, 0, stream>>>(feats, coors, b2e, b1c, w2c, b2c,
                                        w1h, b1h, w2h, b2h,
                                        Q1, P2F, W2F, W1CB, A1B, out);
}

// Round 21
// 59.477 us; speedup vs baseline: 1.0275x; 1.0275x over previous
//
#include <hip/hip_runtime.h>
#include <math.h>
#include <stdint.h>

#define NP 288               // 274 padded to 18*16
#define OUT_H (2*512*64)

typedef _Float16 f16;
typedef __attribute__((ext_vector_type(2))) _Float16 f16x2;
typedef __attribute__((ext_vector_type(4))) _Float16 f16x4;
typedef __attribute__((ext_vector_type(8))) _Float16 f16x8;
typedef __attribute__((ext_vector_type(4))) float f32x4;

static __device__ __forceinline__ f16x2 pkrtz(float a, float b) {
    return __builtin_bit_cast(f16x2, __builtin_amdgcn_cvt_pkrtz(a, b));
}

#if defined(__has_builtin)
#if __has_builtin(__builtin_amdgcn_mfma_f32_16x16x16f16)
#define HAVE_MFMA16 1
#endif
#endif

static __device__ __forceinline__ f32x4 mfma16(f16x4 a, f16x4 b, f32x4 c) {
#ifdef HAVE_MFMA16
    return __builtin_amdgcn_mfma_f32_16x16x16f16(a, b, c, 0, 0, 0);
#else
    f32x4 d;
    asm volatile("v_mfma_f32_16x16x16_f16 %0, %1, %2, %3\n\ts_nop 7\n\ts_nop 7"
                 : "=v"(d) : "v"(a), "v"(b), "v"(c));
    return d;
#endif
}

// relu + pack f32x4 -> f16x4 (pkrtz monotone & exact at 0 -> pack-then-max ok)
static __device__ __forceinline__ f16x4 relupack(f32x4 h) {
    f16x2 lo = pkrtz(h[0], h[1]);
    f16x2 hi = pkrtz(h[2], h[3]);
    const f16x2 z = {(_Float16)0, (_Float16)0};
    lo = __builtin_elementwise_max(lo, z);
    hi = __builtin_elementwise_max(hi, z);
    return __builtin_shufflevector(lo, hi, 0, 1, 2, 3);
}

// ---------------------------------------------------------------------------
// Kernel A: precompute
//   Q1[n][288] f16  = b1e + feats[n] @ w1e[0:64]   (i-side, includes bias)
//   P2F f32 [b][32jt][18S][64lane]x4 = C-fragment-ordered j-side projection
//   W2F[18][64]x4 f16 = per-lane B2 fragments
//   W1CB[4][16][32] f16 = w1c^T blocks (coor-MLP A-frag source)
//   A1B[18][64]x4 f16 = i-independent A1 frags (Wd rows; Q1 slot zeroed)
// ---------------------------------------------------------------------------
__global__ __launch_bounds__(256) void egnn_pre(
    const float* __restrict__ feats, const float* __restrict__ w1e,
    const float* __restrict__ b1e,   const float* __restrict__ w2e,
    const float* __restrict__ w1c,
    f16* __restrict__ Q1, float* __restrict__ P2F,
    f16* __restrict__ W2F, f16* __restrict__ W1CB, f16* __restrict__ A1B)
{
    int id = blockIdx.x * 256 + threadIdx.x;
    const int NN = 1024 * NP;
    if (id < 2 * NN) {
        int hf = id / NN, r = id % NN;
        int n = r / NP, e = r % NP;
        float a = 0.f;
        if (e < 274) {
            a = hf ? 0.f : b1e[e];
            const float* fp = feats + n * 64;
            const float* wp = w1e + hf * 64 * 274 + e;
            #pragma unroll 8
            for (int d2 = 0; d2 < 64; ++d2) a += fp[d2] * wp[d2 * 274];
        }
        if (hf) {
            int b = n >> 9, j = n & 511;
            int jt = j >> 4, cl = j & 15;
            int S = e >> 4, gg = (e >> 2) & 3, jj = e & 3;
            P2F[(((b * 32 + jt) * 18 + S) * 64 + (cl + 16 * gg)) * 4 + jj] = a;
        } else {
            Q1[n * NP + e] = (f16)a;
        }
    } else {
        int x = id - 2 * NN;
        if (x < 1152) {
            // W2F
            int S = x >> 6, l = x & 63, cc = l & 15, gg = l >> 4;
            f16x4 v = {0, 0, 0, 0};
            #pragma unroll
            for (int jj = 0; jj < 4; ++jj) {
                int e = S * 16 + gg * 4 + jj;
                v[jj] = (f16)(e < 274 ? w2e[e * 16 + cc] : 0.f);
            }
            *(f16x4*)(W2F + x * 4) = v;
        } else if (x < 1152 + 2048) {
            int y = x - 1152;
            int T = y >> 9, rem = y & 511, c2 = rem >> 5, k = rem & 31;
            W1CB[y] = (f16)(k < 16 ? w1c[k * 64 + T * 16 + c2] : 0.f);
        } else if (x < 1152 + 2048 + 1152) {
            // A1B (i-independent part of A1 frags)
            int y = x - 1152 - 2048;
            int S = y >> 6, l = y & 63, cc = l & 15, gg = l >> 4;
            int e = S * 16 + cc;
            f16x4 v = {0, 0, 0, 0};
            if (e < 274) {
                if (gg == 0) {
                    v[0] = (f16)w1e[128 * 274 + e]; v[1] = (f16)w1e[129 * 274 + e];
                    v[2] = (f16)w1e[130 * 274 + e]; v[3] = (f16)w1e[131 * 274 + e];
                } else if (gg == 1) {
                    v[0] = (f16)w1e[132 * 274 + e]; v[1] = (f16)w1e[133 * 274 + e];
                    v[2] = (f16)w1e[134 * 274 + e]; v[3] = (f16)w1e[135 * 274 + e];
                } else if (gg == 2) {
                    v[0] = (f16)w1e[136 * 274 + e]; // v[1] = Q1 slot, inserted per block
                }
            }
            *(f16x4*)(A1B + y * 4) = v;
        }
    }
}

// ---------------------------------------------------------------------------
// Kernel B: one block per (b,i) — 1024 blocks, 4 waves x 128 j each.
// Monolithic (round-12 structure): no cross-block combining, direct out.
// Phase 1: 2-unit ILP, S pairs, 2-gen static f32-frag prefetch (coalesced
//   1-KB wave bursts feed MFMA C directly — no cvt).
// Phase 2: coor MLP via MFMA, reductions, node MLP.
// ---------------------------------------------------------------------------
__global__ __launch_bounds__(256) void egnn_edge(
    const float* __restrict__ feats, const float* __restrict__ coors,
    const float* __restrict__ b2e,   const float* __restrict__ b1c,
    const float* __restrict__ w2c,   const float* __restrict__ b2cv,
    const float* __restrict__ w1h,   const float* __restrict__ b1h,
    const float* __restrict__ w2h,   const float* __restrict__ b2h,
    const f16* __restrict__ Q1,  const float* __restrict__ P2F,
    const f16* __restrict__ W2F, const f16* __restrict__ W1CB,
    const f16* __restrict__ A1B, float* __restrict__ out)
{
    __shared__ f16x4 sA1f[1152];        // 9216 B
    __shared__ f16x4 sB2f[1152];        // 9216 B
    __shared__ __align__(16) f16 sM[512 * 16];   // 16384 B
    __shared__ float sHid[128];
    __shared__ float sRedM[4][16];
    __shared__ float sRedC[4][3];
    __shared__ float sFin[16];

    const int bi = blockIdx.x, bb = bi >> 9;
    const int t = threadIdx.x;
    const int lane = t & 63, wv = t >> 6;
    const int c = lane & 15, g = lane >> 4;

    // ---- block init: coalesced copies + per-i Q1 insert (looped: 288>256) --
    {
        const uint2* srcA = (const uint2*)A1B;
        const uint2* srcB = (const uint2*)W2F;
        uint2* dstA = (uint2*)sA1f;
        uint2* dstB = (uint2*)sB2f;
        for (int x = t; x < 1152; x += 256) { dstA[x] = srcA[x]; dstB[x] = srcB[x]; }
    }
    __syncthreads();
    {
        const f16* Q1r = Q1 + bi * NP;
        for (int x = t; x < 288; x += 256) {
            int S = x >> 4, cc = x & 15;
            sA1f[S * 64 + 32 + cc][1] = Q1r[S * 16 + cc];
        }
    }
    const float b2e_c = b2e[c];
    const float cix = coors[bi * 3 + 0];
    const float ciy = coors[bi * 3 + 1];
    const float ciz = coors[bi * 3 + 2];
    __syncthreads();

    const float* P2Fb = P2F + (bb << 5) * 18 * 256;   // [32jt][18S][256] f32

    // ================= Phase 1: edge MLP, 2-unit ILP + 2-gen prefetch =======
    #pragma unroll 1
    for (int pass = 0; pass < 2; ++pass) {
        const int jbase = wv * 128 + pass * 64;
        #pragma unroll 1
        for (int pr = 0; pr < 2; ++pr) {
            f16x4 b1u[2];
            const float* cpp[2];
            #pragma unroll
            for (int u = 0; u < 2; ++u) {
                const int jt = (jbase >> 4) + pr * 2 + u;
                const int j = jbase + (pr * 2 + u) * 16 + c;
                const int jg = (bb << 9) + j;
                float rx = cix - coors[jg * 3 + 0];
                float ry = ciy - coors[jg * 3 + 1];
                float rz = ciz - coors[jg * 3 + 2];
                float sq = rx * rx + ry * ry + rz * rz;
                float d = sq > 0.f ? sqrtf(sq) : 0.f;
                // enc via 1 sincos + double-angle ladder (d/8 -> d/4 -> d/2 -> d)
                float s8, c8v;
                __sincosf(d * 0.125f, &s8, &c8v);
                float s4 = 2.f * s8 * c8v, c4v = 1.f - 2.f * s8 * s8;
                float s2 = 2.f * s4 * c4v, c2v = 1.f - 2.f * s4 * s4;
                float s1 = 2.f * s2 * c2v, c1v = 1.f - 2.f * s2 * s2;
                f16x2 p01 = pkrtz(s1, s2);     // sin(d), sin(d/2)
                f16x2 p23 = pkrtz(s4, s8);     // sin(d/4), sin(d/8)
                f16x2 p45 = pkrtz(c1v, c2v);   // cos(d), cos(d/2)
                f16x2 p67 = pkrtz(c4v, c8v);   // cos(d/4), cos(d/8)
                f16x2 pd1 = pkrtz(d, 1.0f);
                f16x2 zz = {(_Float16)0, (_Float16)0};
                f16x2 lo = (g == 0) ? p01 : (g == 1) ? p45 : (g == 2) ? pd1 : zz;
                f16x2 hi = (g == 0) ? p23 : (g == 1) ? p67 : zz;
                b1u[u] = __builtin_shufflevector(lo, hi, 0, 1, 2, 3);
                cpp[u] = P2Fb + jt * 18 * 256 + lane * 4;   // frag base, +S*256/step
            }

            f32x4 acc0 = {0,0,0,0}, acc1 = {0,0,0,0};
            // prologue: f32 C-frags for S=0,1 (both units)
            f32x4 c0A = *(const f32x4*)(cpp[0]);
            f32x4 c0B = *(const f32x4*)(cpp[1]);
            f32x4 c1A = *(const f32x4*)(cpp[0] + 256);
            f32x4 c1B = *(const f32x4*)(cpp[1] + 256);

            #pragma unroll
            for (int S2 = 0; S2 < 9; ++S2) {
                const int S = 2 * S2;
                f32x4 n0A, n0B, n1A, n1B;
                if (S2 < 8) {
                    n0A = *(const f32x4*)(cpp[0] + (S + 2) * 256);
                    n0B = *(const f32x4*)(cpp[1] + (S + 2) * 256);
                    n1A = *(const f32x4*)(cpp[0] + (S + 3) * 256);
                    n1B = *(const f32x4*)(cpp[1] + (S + 3) * 256);
                }
                // ---- step S ----
                {
                    f16x4 a1 = sA1f[S * 64 + lane];
                    f16x4 b2 = sB2f[S * 64 + lane];
                    f32x4 h0 = mfma16(a1, b1u[0], c0A);
                    f32x4 h1 = mfma16(a1, b1u[1], c0B);
                    acc0 = mfma16(relupack(h0), b2, acc0);
                    acc1 = mfma16(relupack(h1), b2, acc1);
                }
                // ---- step S+1 ----
                {
                    f16x4 a1 = sA1f[(S + 1) * 64 + lane];
                    f16x4 b2 = sB2f[(S + 1) * 64 + lane];
                    f32x4 h0 = mfma16(a1, b1u[0], c1A);
                    f32x4 h1 = mfma16(a1, b1u[1], c1B);
                    acc0 = mfma16(relupack(h0), b2, acc0);
                    acc1 = mfma16(relupack(h1), b2, acc1);
                }
                c0A = n0A; c0B = n0B; c1A = n1A; c1B = n1B;
            }

            #pragma unroll
            for (int u = 0; u < 2; ++u) {
                const int jr = jbase + (pr * 2 + u) * 16 + g * 4;
                const f32x4 accu = u ? acc1 : acc0;
                #pragma unroll
                for (int r = 0; r < 4; ++r)
                    sM[(jr + r) * 16 + c] = (f16)(accu[r] + b2e_c);
            }
        }
    }
    __syncthreads();

    // ================= Phase 2: coor MLP via MFMA =================
    f16x8 aW[4];
    f32x4 b1cL[4], w2cL[4];
    #pragma unroll
    for (int T = 0; T < 4; ++T) {
        aW[T] = *(const f16x8*)(W1CB + (T * 16 + c) * 32 + g * 8);
        b1cL[T] = *(const f32x4*)(b1c + T * 16 + g * 4);
        w2cL[T] = *(const f32x4*)(w2c + T * 16 + g * 4);
    }
    const float b2c0 = b2cv[0];

    float cax = 0.f, cay = 0.f, caz = 0.f;
    float macc8[8] = {0.f,0.f,0.f,0.f,0.f,0.f,0.f,0.f};

    #pragma unroll 1
    for (int jt = 0; jt < 8; ++jt) {
        const int jrow = wv * 128 + jt * 16;
        f16x8 bm = {0,0,0,0,0,0,0,0};
        if (g < 2) {
            bm = *(const f16x8*)(sM + (jrow + c) * 16 + g * 8);
            #pragma unroll
            for (int p = 0; p < 8; ++p) macc8[p] += (float)bm[p];
        }
        f32x4 zc = {0,0,0,0};
        float cwp = 0.f;
        #pragma unroll
        for (int T = 0; T < 4; ++T) {
            f32x4 hd = __builtin_amdgcn_mfma_f32_16x16x32_f16(aW[T], bm, zc, 0, 0, 0);
            #pragma unroll
            for (int r = 0; r < 4; ++r)
                cwp += fmaxf(hd[r] + b1cL[T][r], 0.f) * w2cL[T][r];
        }
        cwp += __shfl_xor(cwp, 16);
        cwp += __shfl_xor(cwp, 32);
        float cw = cwp + b2c0;

        int jg = (bb << 9) + jrow + c;
        float rx = cix - coors[jg * 3 + 0];
        float ry = ciy - coors[jg * 3 + 1];
        float rz = ciz - coors[jg * 3 + 2];
        cax += cw * rx; cay += cw * ry; caz += cw * rz;
    }

    // m_i: reduce macc8 over the 16 c-lanes (butterfly)
    #pragma unroll
    for (int msk = 1; msk <= 8; msk <<= 1)
        #pragma unroll
        for (int p = 0; p < 8; ++p) macc8[p] += __shfl_xor(macc8[p], msk);
    if (c == 0 && g < 2) {
        #pragma unroll
        for (int p = 0; p < 8; ++p) sRedM[wv][g * 8 + p] = macc8[p];
    }
    // coors: full-wave reduce (each edge counted 4x -> scale 0.25 at the end)
    #pragma unroll
    for (int msk = 1; msk <= 32; msk <<= 1) {
        cax += __shfl_xor(cax, msk);
        cay += __shfl_xor(cay, msk);
        caz += __shfl_xor(caz, msk);
    }
    if (lane == 0) { sRedC[wv][0] = cax; sRedC[wv][1] = cay; sRedC[wv][2] = caz; }
    __syncthreads();

    if (t < 16) sFin[t] = sRedM[0][t] + sRedM[1][t] + sRedM[2][t] + sRedM[3][t];
    if (t >= 32 && t < 35) {
        int k = t - 32;
        out[OUT_H + bi * 3 + k] =
            (sRedC[0][k] + sRedC[1][k] + sRedC[2][k] + sRedC[3][k]) * 0.25f;
    }
    __syncthreads();

    // ================= node MLP =================
    if (t < 128) {
        float a = b1h[t];
        const float* fp = feats + bi * 64;
        #pragma unroll 8
        for (int k = 0; k < 64; ++k) a += fp[k] * w1h[k * 128 + t];
        #pragma unroll
        for (int k = 0; k < 16; ++k) a += sFin[k] * w1h[(64 + k) * 128 + t];
        sHid[t] = fmaxf(a, 0.f);
    }
    __syncthreads();
    if (t < 64) {
        float a = b2h[t];
        #pragma unroll 8
        for (int k = 0; k < 128; ++k) a += sHid[k] * w2h[k * 64 + t];
        out[bi * 64 + t] = a;
    }
}

extern "C" void kernel_launch(void* const* d_in, const int* in_sizes, int n_in,
                              void* d_out, int out_size, void* d_ws, size_t ws_size,
                              hipStream_t stream)
{
    const float* feats = (const float*)d_in[0];
    const float* coors = (const float*)d_in[1];
    const float* w1e   = (const float*)d_in[2];
    const float* b1e   = (const float*)d_in[3];
    const float* w2e   = (const float*)d_in[4];
    const float* b2e   = (const float*)d_in[5];
    const float* w1c   = (const float*)d_in[6];
    const float* b1c   = (const float*)d_in[7];
    const float* w2c   = (const float*)d_in[8];
    const float* b2c   = (const float*)d_in[9];
    const float* w1h   = (const float*)d_in[10];
    const float* b1h   = (const float*)d_in[11];
    const float* w2h   = (const float*)d_in[12];
    const float* b2h   = (const float*)d_in[13];
    float* out = (float*)d_out;

    char* ws = (char*)d_ws;
    f16*   Q1    = (f16*)ws;                        // 589824 B
    float* P2F   = (float*)(ws + 589824);           // 1179648 B (frag order, f32)
    f16*   W2F   = (f16*)(ws + 1769472);            // 9216 B
    f16*   W1CB  = (f16*)(ws + 1778688);            // 4096 B
    f16*   A1B   = (f16*)(ws + 1782784);            // 9216 B

    egnn_pre<<<2321, 256, 0, stream>>>(feats, w1e, b1e, w2e, w1c,
                                       Q1, P2F, W2F, W1CB, A1B);
    egnn_edge<<<1024, 256, 0, stream>>>(feats, coors, b2e, b1c, w2c, b2c,
                                        w1h, b1h, w2h, b2h,
                                        Q1, P2F, W2F, W1CB, A1B, out);
}